// Round 6
// baseline (368.703 us; speedup 1.0000x reference)
//
#include <hip/hip_runtime.h>
#include <hip/hip_cooperative_groups.h>
#include <math.h>

namespace cg = cooperative_groups;

typedef unsigned int u32;
typedef float nfloat4 __attribute__((ext_vector_type(4)));

// ---------------------------------------------------------------------------
// Exact 0.99-quantile of |x| via windowed speculative histogram + exact
// fallback. Ladder: R0 75us/pass (LDS-atomic hist). R1 244us (ballot+rtn
// chain). R2/R3 130-138us (256-thr geometry: occupancy 45-54%). R4 274us
// TOTAL (WIN: 512x1024 + scan 4-deep / quantize 2+2). R5 283us (deeper MLP
// regressed -> depth exhausted). R6 (this): known device work sums ~140us
// vs 274 measured -- ~130us is dispatch-boundary overhead. FUSE the whole
// pipeline into ONE cooperative kernel (grid.sync between phases; fast
// path = 3 syncs). Hot-loop bodies are the R4-proven ones, bit-identical
// selection algorithm (absmax 0.0): branchless counters + fire-and-forget
// global atomicAdd into 3x1M-bin window hist for the ~2.2% of elems in
// [2.25,3.0) (covers N(0,1) q99=2.576+/-0.002 at >30 sigma). Fallback (any
// other dist) runs INSIDE fused via grid-uniform branch (full 2048-bin g1,
// then full re-scan -> H2SLOW). If cooperative launch is unsupported/fails
// or ws too small: exact R4 multi-kernel path (kept verbatim below).
// Phases (fused):
//  P0 zero ws  -> sync
//  P1 scan     -> bc[4], h2win (atomics)  -> sync
//  P2 bad? (grid-uniform)  [fb_top -> sync ; fb_low -> sync]
//  P3 chunk sums -> cs[1024] -> sync
//  P4 quantize (prologue re-derives scale redundantly per block)
// ws layout (u32): [0..2047] g1 | [2048..3071] cs | [3072..3075] bc |
//   [3076] FLAG | [4096..4096+1M) H2SLOW | [4096+1M .. 4096+4M) H2WIN
// ---------------------------------------------------------------------------

#define G1 0
#define CS 2048
#define BC 3072
#define FLAG 3076
#define H2S 4096
#define H2W (4096 + (1 << 20))
#define ZERO_SLOW (4096 + (1 << 20))
#define ZERO_FAST (4096 + (1 << 20) + 3 * (1 << 20))
#define WIN_LO 1025u
#define WIN_HI 1027u
#define LOBITS (WIN_LO << 20)
#define SPANBITS ((WIN_HI - WIN_LO + 1u) << 20)

#define PROC_BODY(raw)                                     \
  do {                                                     \
    const u32 a_ = (raw) & 0x7fffffffu;                    \
    const u32 d_ = a_ - LOBITS;                            \
    const bool in_ = d_ < SPANBITS;                        \
    bel += (a_ < LOBITS) ? 1u : 0u;                        \
    tk += in_ ? 1u : 0u;                                   \
    w0 += (in_ && d_ < (1u << 20)) ? 1u : 0u;              \
    w2 += (in_ && d_ >= (2u << 20)) ? 1u : 0u;             \
    if (in_) atomicAdd(&h2w[d_], 1u);                      \
  } while (0)

// ============================ FUSED (fast) =================================
__global__ __launch_bounds__(1024, 8) void fused_all(
    const u32* __restrict__ x, float* __restrict__ out, u32* __restrict__ ws,
    const float* __restrict__ gamma, long long n, u32 k) {
  cg::grid_group grid = cg::this_grid();
  __shared__ u32 h[2048 * 8];  // 64 KB: fallback hist / prefix-scan buffer
  __shared__ u32 red[16][4];
  __shared__ u32 r0, r1;
  __shared__ float fscale;
  const int t = threadIdx.x;
  const long long NB = gridDim.x;
  const long long GT = NB * 1024;
  const long long n4 = n >> 2;

  // ---- P0: zero workspace ----
  for (long long i = (long long)blockIdx.x * 1024 + t; i < (long long)ZERO_FAST;
       i += GT)
    ws[i] = 0u;
  grid.sync();

  // ---- P1: scan (R4 body, 4 loads in flight) ----
  {
    u32* bc = ws + BC;
    u32* h2w = ws + H2W;
    u32 bel = 0, w0 = 0, w2 = 0, tk = 0;
    const uint4* x4 = (const uint4*)x;
#define PROC4(v)                                                           \
  do { PROC_BODY((v).x); PROC_BODY((v).y); PROC_BODY((v).z); PROC_BODY((v).w); } while (0)
    const long long CH = NB * 4096;
    long long i = (long long)blockIdx.x * 4096 + t;
    for (; i + 3072 < n4; i += CH) {
      uint4 va = x4[i];
      uint4 vb = x4[i + 1024];
      uint4 vc = x4[i + 2048];
      uint4 vd = x4[i + 3072];
      PROC4(va);
      PROC4(vb);
      PROC4(vc);
      PROC4(vd);
    }
    for (int q = 0; q < 3; ++q, i += 1024)
      if (i < n4) {
        uint4 v = x4[i];
        PROC4(v);
      }
    for (long long j = (n4 << 2) + (long long)blockIdx.x * 1024 + t; j < n;
         j += GT)
      PROC_BODY(x[j]);
#undef PROC4
#pragma unroll
    for (int off = 32; off > 0; off >>= 1) {
      bel += __shfl_down(bel, off, 64);
      w0 += __shfl_down(w0, off, 64);
      w2 += __shfl_down(w2, off, 64);
      tk += __shfl_down(tk, off, 64);
    }
    if ((t & 63) == 0) {
      const int w = t >> 6;
      red[w][0] = bel;
      red[w][1] = w0;
      red[w][2] = w2;
      red[w][3] = tk;
    }
    __syncthreads();
    if (t == 0) {
      u32 B = 0, W0 = 0, W2 = 0, TK = 0;
#pragma unroll
      for (int w = 0; w < 16; ++w) {
        B += red[w][0];
        W0 += red[w][1];
        W2 += red[w][2];
        TK += red[w][3];
      }
      if (B) atomicAdd(&bc[0], B);
      if (W0) atomicAdd(&bc[1], W0);
      const u32 W1 = TK - W0 - W2;
      if (W1) atomicAdd(&bc[2], W1);
      if (W2) atomicAdd(&bc[3], W2);
    }
  }
  grid.sync();

  // ---- grid-uniform validity ----
  const u32 below = ws[BC], W0 = ws[BC + 1], W1 = ws[BC + 2], W2 = ws[BC + 3];
  const bool bad = (k < below) || ((k - below) >= W0 + W1 + W2);

  if (bad) {  // grid-uniform branch: all blocks take it or none do
    // ---- P2a: full 2048-bin top hist -> g1 (8-replica LDS) ----
    {
      u32* g1 = ws + G1;
      for (int i = t; i < 2048 * 8; i += 1024) h[i] = 0;
      __syncthreads();
      const u32 r = (u32)(t & 7);
      const uint4* x4 = (const uint4*)x;
      for (long long i = (long long)blockIdx.x * 1024 + t; i < n4; i += GT) {
        uint4 v = x4[i];
        atomicAdd(&h[(((v.x & 0x7fffffffu) >> 20) << 3) + r], 1u);
        atomicAdd(&h[(((v.y & 0x7fffffffu) >> 20) << 3) + r], 1u);
        atomicAdd(&h[(((v.z & 0x7fffffffu) >> 20) << 3) + r], 1u);
        atomicAdd(&h[(((v.w & 0x7fffffffu) >> 20) << 3) + r], 1u);
      }
      for (long long i = (n4 << 2) + (long long)blockIdx.x * 1024 + t; i < n;
           i += GT)
        atomicAdd(&h[(((x[i] & 0x7fffffffu) >> 20) << 3) + r], 1u);
      __syncthreads();
      for (int i = t; i < 2048; i += 1024) {
        u32 c = 0;
#pragma unroll
        for (int j = 0; j < 8; ++j) c += h[(i << 3) + j];
        if (c) atomicAdd(&g1[i], c);
      }
    }
    grid.sync();
    // ---- P2b: B1 from g1; full scan -> H2SLOW ----
    {
      u32* s = h;
      const u32* g1 = ws + G1;
      u32* h2 = ws + H2S;
      const uint2 c2 = ((const uint2*)g1)[t];
      const u32 sum = c2.x + c2.y;
      s[t] = sum;
      __syncthreads();
      for (int off = 1; off < 1024; off <<= 1) {
        u32 add = (t >= off) ? s[t - off] : 0u;
        __syncthreads();
        s[t] += add;
        __syncthreads();
      }
      u32 ex = s[t] - sum;
      if (k >= ex && k < ex + c2.x) r0 = 2u * t;
      ex += c2.x;
      if (k >= ex && k < ex + c2.y) r0 = 2u * t + 1u;
      __syncthreads();
      const u32 B1 = r0;
      const uint4* x4 = (const uint4*)x;
      for (long long i = (long long)blockIdx.x * 1024 + t; i < n4; i += GT) {
        uint4 v = x4[i];
        u32 a;
        a = v.x & 0x7fffffffu; if ((a >> 20) == B1) atomicAdd(&h2[a & 0xFFFFFu], 1u);
        a = v.y & 0x7fffffffu; if ((a >> 20) == B1) atomicAdd(&h2[a & 0xFFFFFu], 1u);
        a = v.z & 0x7fffffffu; if ((a >> 20) == B1) atomicAdd(&h2[a & 0xFFFFFu], 1u);
        a = v.w & 0x7fffffffu; if ((a >> 20) == B1) atomicAdd(&h2[a & 0xFFFFFu], 1u);
      }
      for (long long i = (n4 << 2) + (long long)blockIdx.x * 1024 + t; i < n;
           i += GT) {
        const u32 a = x[i] & 0x7fffffffu;
        if ((a >> 20) == B1) atomicAdd(&h2[a & 0xFFFFFu], 1u);
      }
      __syncthreads();
    }
    grid.sync();
  }

  // ---- P3: chunk sums -> cs[1024] ----
  {
    const u32* base;
    u32 slot = 0;
    if (bad) {
      base = ws + H2S;
    } else {
      const u32 sub = k - below;
      slot = (sub < W0) ? 0u : ((sub < W0 + W1) ? 1u : 2u);
      base = ws + H2W + ((size_t)slot << 20);
    }
    u32* cs = ws + CS;
    for (u32 c = (u32)blockIdx.x; c < 1024u; c += (u32)NB) {
      u32 sum = base[(size_t)c * 1024 + t];
#pragma unroll
      for (int off = 32; off > 0; off >>= 1) sum += __shfl_down(sum, off, 64);
      if ((t & 63) == 0) red[t >> 6][0] = sum;
      __syncthreads();
      if (t == 0) {
        u32 s16 = 0;
#pragma unroll
        for (int w = 0; w < 16; ++w) s16 += red[w][0];
        cs[c] = s16;
      }
      __syncthreads();
    }
  }
  grid.sync();

  // ---- P4: quantize ----
  {
    u32* s = h;
    const u32* cs = ws + CS;
    // (B1, k1)
    u32 B1, k1;
    const u32* h2base;
    if (!bad) {
      const u32 sub = k - below;
      u32 slot;
      if (sub < W0) {
        slot = 0u; k1 = sub;
      } else if (sub < W0 + W1) {
        slot = 1u; k1 = sub - W0;
      } else {
        slot = 2u; k1 = sub - W0 - W1;
      }
      B1 = WIN_LO + slot;
      h2base = ws + H2W + ((size_t)slot << 20);
    } else {
      const uint2 c2 = ((const uint2*)(ws + G1))[t];
      const u32 sum = c2.x + c2.y;
      s[t] = sum;
      __syncthreads();
      for (int off = 1; off < 1024; off <<= 1) {
        u32 add = (t >= off) ? s[t - off] : 0u;
        __syncthreads();
        s[t] += add;
        __syncthreads();
      }
      u32 ex = s[t] - sum;
      if (k >= ex && k < ex + c2.x) { r0 = 2u * t; r1 = k - ex; }
      ex += c2.x;
      if (k >= ex && k < ex + c2.y) { r0 = 2u * t + 1u; r1 = k - ex; }
      __syncthreads();
      B1 = r0; k1 = r1;
      h2base = ws + H2S;
    }
    // (chunk, k2)
    u32 chunk, k2;
    {
      const u32 c = cs[t];
      __syncthreads();
      s[t] = c;
      __syncthreads();
      for (int off = 1; off < 1024; off <<= 1) {
        u32 add = (t >= off) ? s[t - off] : 0u;
        __syncthreads();
        s[t] += add;
        __syncthreads();
      }
      u32 ex = s[t] - c;
      if (k1 >= ex && k1 < ex + c) { r0 = (u32)t; r1 = k1 - ex; }
      __syncthreads();
      chunk = r0; k2 = r1;
    }
    // exact bits -> scale
    {
      const u32 c = h2base[(size_t)chunk * 1024 + t];
      __syncthreads();
      s[t] = c;
      __syncthreads();
      for (int off = 1; off < 1024; off <<= 1) {
        u32 add = (t >= off) ? s[t - off] : 0u;
        __syncthreads();
        s[t] += add;
        __syncthreads();
      }
      u32 ex = s[t] - c;
      if (k2 >= ex && k2 < ex + c) {
        const u32 bits = (B1 << 20) | (chunk * 1024u + (u32)t);
        const float q = __uint_as_float(bits);
        float gm = gamma[0];
        gm = fminf(fmaxf(gm, 0.1f), 10.0f);
        fscale = (q / 127.0f) * gm;
      }
      __syncthreads();
    }
    const float scale = fscale;

    const float4* x4 = (const float4*)x;
    nfloat4* o4 = (nfloat4*)out;
#define QUANT(v, o)                                                        \
  do {                                                                     \
    (o).x = fminf(fmaxf(rintf((v).x / scale), -128.0f), 127.0f) * scale;   \
    (o).y = fminf(fmaxf(rintf((v).y / scale), -128.0f), 127.0f) * scale;   \
    (o).z = fminf(fmaxf(rintf((v).z / scale), -128.0f), 127.0f) * scale;   \
    (o).w = fminf(fmaxf(rintf((v).w / scale), -128.0f), 127.0f) * scale;   \
  } while (0)
    const long long CH = NB * 2048;
    long long i = (long long)blockIdx.x * 2048 + t;
    for (; i + 1024 < n4; i += CH) {
      float4 va = x4[i];
      float4 vb = x4[i + 1024];
      nfloat4 oa, ob;
      QUANT(va, oa);
      QUANT(vb, ob);
      __builtin_nontemporal_store(oa, &o4[i]);
      __builtin_nontemporal_store(ob, &o4[i + 1024]);
    }
    if (i < n4) {
      float4 v = x4[i];
      nfloat4 o;
      QUANT(v, o);
      __builtin_nontemporal_store(o, &o4[i]);
    }
#undef QUANT
    for (long long j = (n4 << 2) + (long long)blockIdx.x * 1024 + t; j < n;
         j += GT) {
      float v = x[j];
      out[j] = fminf(fmaxf(rintf(v / scale), -128.0f), 127.0f) * scale;
    }
  }
}

// ===================== R4 multi-kernel path (fallback) =====================
__global__ __launch_bounds__(1024) void scan_top(const u32* __restrict__ x,
                                                 u32* __restrict__ ws,
                                                 long long n, int do_cap) {
  u32* bc = ws + BC;
  u32* h2w = ws + H2W;
  __shared__ u32 red[16][4];
  const int t = threadIdx.x;
  u32 bel = 0, w0 = 0, w2 = 0, tk = 0;
  const long long n4 = n >> 2;
  const uint4* x4 = (const uint4*)x;
#define PROC(raw)                                          \
  do {                                                     \
    const u32 a_ = (raw) & 0x7fffffffu;                    \
    const u32 d_ = a_ - LOBITS;                            \
    const bool in_ = d_ < SPANBITS;                        \
    bel += (a_ < LOBITS) ? 1u : 0u;                        \
    tk += in_ ? 1u : 0u;                                   \
    w0 += (in_ && d_ < (1u << 20)) ? 1u : 0u;              \
    w2 += (in_ && d_ >= (2u << 20)) ? 1u : 0u;             \
    if (do_cap && in_) atomicAdd(&h2w[d_], 1u);            \
  } while (0)
#define PROC4(v) do { PROC((v).x); PROC((v).y); PROC((v).z); PROC((v).w); } while (0)
  const long long CH = (long long)gridDim.x * 4096;
  long long i = (long long)blockIdx.x * 4096 + t;
  for (; i + 3072 < n4; i += CH) {
    uint4 va = x4[i];
    uint4 vb = x4[i + 1024];
    uint4 vc = x4[i + 2048];
    uint4 vd = x4[i + 3072];
    PROC4(va);
    PROC4(vb);
    PROC4(vc);
    PROC4(vd);
  }
  for (int q = 0; q < 3; ++q, i += 1024)
    if (i < n4) {
      uint4 v = x4[i];
      PROC4(v);
    }
  for (long long j = (n4 << 2) + (long long)blockIdx.x * 1024 + t; j < n;
       j += (long long)gridDim.x * 1024)
    PROC(x[j]);
#undef PROC4
#undef PROC
#pragma unroll
  for (int off = 32; off > 0; off >>= 1) {
    bel += __shfl_down(bel, off, 64);
    w0 += __shfl_down(w0, off, 64);
    w2 += __shfl_down(w2, off, 64);
    tk += __shfl_down(tk, off, 64);
  }
  if ((t & 63) == 0) {
    const int w = t >> 6;
    red[w][0] = bel;
    red[w][1] = w0;
    red[w][2] = w2;
    red[w][3] = tk;
  }
  __syncthreads();
  if (t == 0) {
    u32 B = 0, W0 = 0, W2 = 0, TK = 0;
#pragma unroll
    for (int w = 0; w < 16; ++w) {
      B += red[w][0];
      W0 += red[w][1];
      W2 += red[w][2];
      TK += red[w][3];
    }
    if (B) atomicAdd(&bc[0], B);
    if (W0) atomicAdd(&bc[1], W0);
    const u32 W1 = TK - W0 - W2;
    if (W1) atomicAdd(&bc[2], W1);
    if (W2) atomicAdd(&bc[3], W2);
  }
}

__global__ __launch_bounds__(1024) void fb_top(const u32* __restrict__ x,
                                               u32* __restrict__ ws,
                                               long long n, u32 k, int force) {
  __shared__ u32 h[2048 * 8];
  __shared__ int bad;
  const int t = threadIdx.x;
  if (t == 0) {
    bad = force;
    if (!force) {
      const u32 below = ws[BC], W0 = ws[BC + 1], W1 = ws[BC + 2],
                W2 = ws[BC + 3];
      if (k < below || (k - below) >= W0 + W1 + W2) bad = 1;
    }
  }
  __syncthreads();
  if (!bad) return;
  if (t == 0) ws[FLAG] = 1u;

  u32* g1 = ws + G1;
  for (int i = t; i < 2048 * 8; i += 1024) h[i] = 0;
  __syncthreads();
  const u32 r = (u32)(t & 7);
  const long long n4 = n >> 2;
  const long long stride = (long long)gridDim.x * 1024;
  const uint4* x4 = (const uint4*)x;
  for (long long i = (long long)blockIdx.x * 1024 + t; i < n4; i += stride) {
    uint4 v = x4[i];
    atomicAdd(&h[(((v.x & 0x7fffffffu) >> 20) << 3) + r], 1u);
    atomicAdd(&h[(((v.y & 0x7fffffffu) >> 20) << 3) + r], 1u);
    atomicAdd(&h[(((v.z & 0x7fffffffu) >> 20) << 3) + r], 1u);
    atomicAdd(&h[(((v.w & 0x7fffffffu) >> 20) << 3) + r], 1u);
  }
  for (long long i = (n4 << 2) + (long long)blockIdx.x * 1024 + t; i < n;
       i += stride)
    atomicAdd(&h[(((x[i] & 0x7fffffffu) >> 20) << 3) + r], 1u);
  __syncthreads();
  for (int i = t; i < 2048; i += 1024) {
    u32 c = 0;
#pragma unroll
    for (int j = 0; j < 8; ++j) c += h[(i << 3) + j];
    if (c) atomicAdd(&g1[i], c);
  }
}

__global__ __launch_bounds__(1024) void fb_low(const u32* __restrict__ x,
                                               u32* __restrict__ ws,
                                               long long n, u32 k) {
  __shared__ u32 s[1024];
  __shared__ u32 resB1;
  if (ws[FLAG] == 0u) return;

  const u32* g1 = ws + G1;
  u32* h2 = ws + H2S;
  const int t = threadIdx.x;
  {
    const uint2 c2 = ((const uint2*)g1)[t];
    const u32 sum = c2.x + c2.y;
    s[t] = sum;
    __syncthreads();
    for (int off = 1; off < 1024; off <<= 1) {
      u32 add = (t >= off) ? s[t - off] : 0u;
      __syncthreads();
      s[t] += add;
      __syncthreads();
    }
    u32 ex = s[t] - sum;
    if (k >= ex && k < ex + c2.x) resB1 = 2 * t;
    ex += c2.x;
    if (k >= ex && k < ex + c2.y) resB1 = 2 * t + 1;
    __syncthreads();
  }
  const u32 B1 = resB1;

  const long long n4 = n >> 2;
  const long long stride = (long long)gridDim.x * 1024;
  const uint4* x4 = (const uint4*)x;
  for (long long i = (long long)blockIdx.x * 1024 + t; i < n4; i += stride) {
    uint4 v = x4[i];
    u32 a;
    a = v.x & 0x7fffffffu; if ((a >> 20) == B1) atomicAdd(&h2[a & 0xFFFFFu], 1u);
    a = v.y & 0x7fffffffu; if ((a >> 20) == B1) atomicAdd(&h2[a & 0xFFFFFu], 1u);
    a = v.z & 0x7fffffffu; if ((a >> 20) == B1) atomicAdd(&h2[a & 0xFFFFFu], 1u);
    a = v.w & 0x7fffffffu; if ((a >> 20) == B1) atomicAdd(&h2[a & 0xFFFFFu], 1u);
  }
  for (long long i = (n4 << 2) + (long long)blockIdx.x * 1024 + t; i < n;
       i += stride) {
    const u32 a = x[i] & 0x7fffffffu;
    if ((a >> 20) == B1) atomicAdd(&h2[a & 0xFFFFFu], 1u);
  }
}

__global__ __launch_bounds__(256) void chunk_reduce(u32* __restrict__ ws,
                                                    u32 k) {
  const int t = threadIdx.x;
  const u32* base;
  if (ws[FLAG] != 0u) {
    base = ws + H2S;
  } else {
    const u32 below = ws[BC], W0 = ws[BC + 1], W1 = ws[BC + 2];
    const u32 sub = k - below;
    const u32 slot = (sub < W0) ? 0u : ((sub < W0 + W1) ? 1u : 2u);
    base = ws + H2W + ((size_t)slot << 20);
  }
  u32* cs = ws + CS;
  uint4 v = ((const uint4*)(base + (size_t)blockIdx.x * 1024))[t];
  u32 sum = v.x + v.y + v.z + v.w;
#pragma unroll
  for (int off = 32; off > 0; off >>= 1) sum += __shfl_down(sum, off, 64);
  __shared__ u32 w[4];
  if ((t & 63) == 0) w[t >> 6] = sum;
  __syncthreads();
  if (t == 0) cs[blockIdx.x] = w[0] + w[1] + w[2] + w[3];
}

__global__ __launch_bounds__(1024) void quantize(const float* __restrict__ x,
                                                 float* __restrict__ out,
                                                 const u32* __restrict__ ws,
                                                 const float* __restrict__ gamma,
                                                 long long n, u32 k) {
  __shared__ u32 s[1024];
  __shared__ u32 r0, r1;
  __shared__ float fscale;
  const u32* cs = ws + CS;
  const int t = threadIdx.x;
  const int flag = (ws[FLAG] != 0u);

  u32 B1, k1;
  const u32* h2base;
  if (!flag) {
    const u32 below = ws[BC], W0 = ws[BC + 1], W1 = ws[BC + 2];
    const u32 sub = k - below;
    u32 slot;
    if (sub < W0) {
      slot = 0u; k1 = sub;
    } else if (sub < W0 + W1) {
      slot = 1u; k1 = sub - W0;
    } else {
      slot = 2u; k1 = sub - W0 - W1;
    }
    B1 = WIN_LO + slot;
    h2base = ws + H2W + ((size_t)slot << 20);
  } else {
    const uint2 c2 = ((const uint2*)(ws + G1))[t];
    const u32 sum = c2.x + c2.y;
    s[t] = sum;
    __syncthreads();
    for (int off = 1; off < 1024; off <<= 1) {
      u32 add = (t >= off) ? s[t - off] : 0u;
      __syncthreads();
      s[t] += add;
      __syncthreads();
    }
    u32 ex = s[t] - sum;
    if (k >= ex && k < ex + c2.x) { r0 = 2u * t; r1 = k - ex; }
    ex += c2.x;
    if (k >= ex && k < ex + c2.y) { r0 = 2u * t + 1u; r1 = k - ex; }
    __syncthreads();
    B1 = r0; k1 = r1;
    h2base = ws + H2S;
  }
  u32 chunk, k2;
  {
    const u32 c = cs[t];
    __syncthreads();
    s[t] = c;
    __syncthreads();
    for (int off = 1; off < 1024; off <<= 1) {
      u32 add = (t >= off) ? s[t - off] : 0u;
      __syncthreads();
      s[t] += add;
      __syncthreads();
    }
    u32 ex = s[t] - c;
    if (k1 >= ex && k1 < ex + c) { r0 = (u32)t; r1 = k1 - ex; }
    __syncthreads();
    chunk = r0; k2 = r1;
  }
  {
    const u32 c = h2base[(size_t)chunk * 1024 + t];
    __syncthreads();
    s[t] = c;
    __syncthreads();
    for (int off = 1; off < 1024; off <<= 1) {
      u32 add = (t >= off) ? s[t - off] : 0u;
      __syncthreads();
      s[t] += add;
      __syncthreads();
    }
    u32 ex = s[t] - c;
    if (k2 >= ex && k2 < ex + c) {
      const u32 bits = (B1 << 20) | (chunk * 1024u + (u32)t);
      const float q = __uint_as_float(bits);
      float gm = gamma[0];
      gm = fminf(fmaxf(gm, 0.1f), 10.0f);
      fscale = (q / 127.0f) * gm;
    }
    __syncthreads();
  }
  const float scale = fscale;

  const long long n4 = n >> 2;
  const float4* x4 = (const float4*)x;
  nfloat4* o4 = (nfloat4*)out;
#define QUANT(v, o)                                                        \
  do {                                                                     \
    (o).x = fminf(fmaxf(rintf((v).x / scale), -128.0f), 127.0f) * scale;   \
    (o).y = fminf(fmaxf(rintf((v).y / scale), -128.0f), 127.0f) * scale;   \
    (o).z = fminf(fmaxf(rintf((v).z / scale), -128.0f), 127.0f) * scale;   \
    (o).w = fminf(fmaxf(rintf((v).w / scale), -128.0f), 127.0f) * scale;   \
  } while (0)
  const long long CH = (long long)gridDim.x * 2048;
  long long i = (long long)blockIdx.x * 2048 + t;
  for (; i + 1024 < n4; i += CH) {
    float4 va = x4[i];
    float4 vb = x4[i + 1024];
    nfloat4 oa, ob;
    QUANT(va, oa);
    QUANT(vb, ob);
    __builtin_nontemporal_store(oa, &o4[i]);
    __builtin_nontemporal_store(ob, &o4[i + 1024]);
  }
  if (i < n4) {
    float4 v = x4[i];
    nfloat4 o;
    QUANT(v, o);
    __builtin_nontemporal_store(o, &o4[i]);
  }
#undef QUANT
  for (long long j = (n4 << 2) + (long long)blockIdx.x * 1024 + t; j < n;
       j += (long long)gridDim.x * 1024) {
    float v = x[j];
    out[j] = fminf(fmaxf(rintf(v / scale), -128.0f), 127.0f) * scale;
  }
}

extern "C" void kernel_launch(void* const* d_in, const int* in_sizes, int n_in,
                              void* d_out, int out_size, void* d_ws,
                              size_t ws_size, hipStream_t stream) {
  const u32* xbits = (const u32*)d_in[0];
  const float* gamma = (const float*)d_in[1];
  float* outp = (float*)d_out;
  long long n = (long long)in_sizes[0];
  u32* ws = (u32*)d_ws;
  u32 k = (u32)llround(0.99 * (double)n);

  const int cap_ok = (ws_size >= (size_t)ZERO_FAST * sizeof(u32)) ? 1 : 0;

  // one-time cooperative-launch capability probe (host-side queries only;
  // no allocation/sync -- graph-capture safe)
  static int coop_grid = -2;
  if (coop_grid == -2) {
    int dev = 0;
    (void)hipGetDevice(&dev);
    int coop = 0, ncu = 0, nb = 0;
    (void)hipDeviceGetAttribute(&coop, hipDeviceAttributeCooperativeLaunch, dev);
    (void)hipDeviceGetAttribute(&ncu, hipDeviceAttributeMultiprocessorCount,
                                dev);
    hipError_t e =
        hipOccupancyMaxActiveBlocksPerMultiprocessor(&nb, fused_all, 1024, 0);
    if (coop && e == hipSuccess && nb >= 1 && ncu > 0) {
      long long g = (long long)nb * ncu;
      coop_grid = (int)((g > 512) ? 512 : g);
    } else {
      coop_grid = 0;
    }
  }

  bool launched = false;
  if (cap_ok && coop_grid >= 256) {
    void* args[] = {(void*)&xbits, (void*)&outp, (void*)&ws,
                    (void*)&gamma, (void*)&n,    (void*)&k};
    hipError_t e = hipLaunchCooperativeKernel(fused_all, dim3(coop_grid),
                                              dim3(1024), args, 0, stream);
    if (e == hipSuccess)
      launched = true;
    else
      coop_grid = 0;  // don't retry; fall back permanently
  }

  if (!launched) {
    const size_t zero_u32 = cap_ok ? (size_t)ZERO_FAST : (size_t)ZERO_SLOW;
    (void)hipMemsetAsync(ws, 0, zero_u32 * sizeof(u32), stream);
    scan_top<<<512, 1024, 0, stream>>>(xbits, ws, n, cap_ok);
    fb_top<<<512, 1024, 0, stream>>>(xbits, ws, n, k, cap_ok ? 0 : 1);
    fb_low<<<512, 1024, 0, stream>>>(xbits, ws, n, k);
    chunk_reduce<<<1024, 256, 0, stream>>>(ws, k);
    quantize<<<512, 1024, 0, stream>>>((const float*)d_in[0], outp, ws, gamma,
                                       n, k);
  }
}

// Round 7
// 260.435 us; speedup vs baseline: 1.4157x; 1.4157x over previous
//
#include <hip/hip_runtime.h>
#include <math.h>

typedef unsigned int u32;
typedef float nfloat4 __attribute__((ext_vector_type(4)));

// ---------------------------------------------------------------------------
// Exact 0.99-quantile of |x| via NARROW-window speculative histogram + exact
// fallback. Ladder: R0 75us/pass (LDS-atomic hist). R1 244us (ballot+rtn).
// R2/R3 130-138 (256-thr geometry). R4 274 TOTAL (champion: 512x1024, scan
// 4-deep, quantize 2+2). R5 283 (deeper MLP regressed). R6 368 (grid.sync
// fusion regressed: fused dispatch 262 > sum of parts; boundary overhead was
// mis-attributed -- the ~80us fill is harness ws-poison, fixed cost).
// R7 (this): revert to R4 structure; shrink the speculative window 50x to
// bits [0x40230000, 0x40270000) = |x| in [2.546875, 2.609375), 2^18 bins.
// Empirical q99 fraction SE=1.7e-5 -> +/-49 sigma margin. Atomics in the
// scan drop 740K -> ~59K (vmcnt-queue pollution gone), window hist 12MB ->
// 1MB, memset 16.8 -> 5.3MB. Validity is checked EXACTLY (k in [c_lo,
// c_lo+c_in)); any other input -> verbatim R4 fallback: full 2048-bin g1
// (fb_top) + full low-20 re-scan into H2SLOW (fb_low). All visibility via
// kernel boundaries only (fences/tickets regress; grid.sync regresses).
//  K1 scan_top : stream x (4 uint4 in flight); c_lo/c_in reg counters ->
//                bc[2]; in fine window -> fire-and-forget atomicAdd
//                h2fine[a - FINE_LO]
//  K2 fb_top   : k in [c_lo,c_lo+c_in)? exit : FLAG=1, 2048-bin hist -> g1
//  K3 fb_low   : FLAG? scan g1 -> B1, full scan -> H2SLOW : exit
//  K4 chunk_red: fast: blocks<256 sum h2fine chunks -> cs[0..255]
//                slow: 1024 blocks sum H2SLOW chunks -> cs[0..1023]
//  K5 quantize : prologue: fast k1=k-c_lo / slow g1-scan; cs -> (chunk,k2);
//                hist[chunk] -> exact bits -> scale; fake-quantize (2+2)
// ws layout (u32): [0..2047] g1 | [2048..3071] cs | [3072..3073] bc |
//   [3076] FLAG | [4096..4096+1M) H2SLOW | [4096+1M..4096+1M+256K) H2FINE
// ---------------------------------------------------------------------------

#define G1 0
#define CS 2048
#define BC 3072
#define FLAG 3076
#define H2S 4096
#define H2F (4096 + (1 << 20))
#define ZERO_SLOW (4096 + (1 << 20))
#define ZERO_FAST (4096 + (1 << 20) + (1 << 18))
// fine window: |x| in [2.546875, 2.609375) -- 2^18 float-bit patterns
#define FINE_LO 0x40230000u
#define FINE_SPAN 0x40000u

__global__ __launch_bounds__(1024) void scan_top(const u32* __restrict__ x,
                                                 u32* __restrict__ ws,
                                                 long long n, int do_cap) {
  u32* bc = ws + BC;
  u32* h2f = ws + H2F;
  __shared__ u32 red[16][2];
  const int t = threadIdx.x;
  u32 clo = 0, cin = 0;
  const long long n4 = n >> 2;
  const uint4* x4 = (const uint4*)x;

#define PROC(raw)                                          \
  do {                                                     \
    const u32 a_ = (raw) & 0x7fffffffu;                    \
    const u32 d_ = a_ - FINE_LO;                           \
    clo += (a_ < FINE_LO) ? 1u : 0u;                       \
    if (d_ < FINE_SPAN) {                                  \
      cin += 1u;                                           \
      if (do_cap) atomicAdd(&h2f[d_], 1u);                 \
    }                                                      \
  } while (0)
#define PROC4(v) do { PROC((v).x); PROC((v).y); PROC((v).z); PROC((v).w); } while (0)

  const long long CH = (long long)gridDim.x * 4096;
  long long i = (long long)blockIdx.x * 4096 + t;
  for (; i + 3072 < n4; i += CH) {
    uint4 va = x4[i];
    uint4 vb = x4[i + 1024];
    uint4 vc = x4[i + 2048];
    uint4 vd = x4[i + 3072];
    PROC4(va);
    PROC4(vb);
    PROC4(vc);
    PROC4(vd);
  }
  for (int q = 0; q < 3; ++q, i += 1024)
    if (i < n4) {
      uint4 v = x4[i];
      PROC4(v);
    }
  for (long long j = (n4 << 2) + (long long)blockIdx.x * 1024 + t; j < n;
       j += (long long)gridDim.x * 1024)
    PROC(x[j]);
#undef PROC4
#undef PROC

#pragma unroll
  for (int off = 32; off > 0; off >>= 1) {
    clo += __shfl_down(clo, off, 64);
    cin += __shfl_down(cin, off, 64);
  }
  if ((t & 63) == 0) {
    const int w = t >> 6;
    red[w][0] = clo;
    red[w][1] = cin;
  }
  __syncthreads();
  if (t == 0) {
    u32 L = 0, I = 0;
#pragma unroll
    for (int w = 0; w < 16; ++w) {
      L += red[w][0];
      I += red[w][1];
    }
    if (L) atomicAdd(&bc[0], L);
    if (I) atomicAdd(&bc[1], I);
  }
}

// Always enqueued. Fast path: uniform early exit. Bad path: set FLAG, build
// the full 2048-bin g1 (8-replica LDS histogram). Exact for any input.
__global__ __launch_bounds__(1024) void fb_top(const u32* __restrict__ x,
                                               u32* __restrict__ ws,
                                               long long n, u32 k, int force) {
  __shared__ u32 h[2048 * 8];  // 64 KB; no-op on fast path
  __shared__ int bad;
  const int t = threadIdx.x;
  if (t == 0) {
    bad = force;
    if (!force) {
      const u32 clo = ws[BC], cin = ws[BC + 1];
      if (k < clo || (k - clo) >= cin) bad = 1;
    }
  }
  __syncthreads();
  if (!bad) return;  // block-uniform
  if (t == 0) ws[FLAG] = 1u;  // all blocks write 1 -- benign

  u32* g1 = ws + G1;
  for (int i = t; i < 2048 * 8; i += 1024) h[i] = 0;
  __syncthreads();
  const u32 r = (u32)(t & 7);
  const long long n4 = n >> 2;
  const long long stride = (long long)gridDim.x * 1024;
  const uint4* x4 = (const uint4*)x;
  for (long long i = (long long)blockIdx.x * 1024 + t; i < n4; i += stride) {
    uint4 v = x4[i];
    atomicAdd(&h[(((v.x & 0x7fffffffu) >> 20) << 3) + r], 1u);
    atomicAdd(&h[(((v.y & 0x7fffffffu) >> 20) << 3) + r], 1u);
    atomicAdd(&h[(((v.z & 0x7fffffffu) >> 20) << 3) + r], 1u);
    atomicAdd(&h[(((v.w & 0x7fffffffu) >> 20) << 3) + r], 1u);
  }
  for (long long i = (n4 << 2) + (long long)blockIdx.x * 1024 + t; i < n;
       i += stride)
    atomicAdd(&h[(((x[i] & 0x7fffffffu) >> 20) << 3) + r], 1u);
  __syncthreads();
  for (int i = t; i < 2048; i += 1024) {
    u32 c = 0;
#pragma unroll
    for (int j = 0; j < 8; ++j) c += h[(i << 3) + j];
    if (c) atomicAdd(&g1[i], c);
  }
}

// Always enqueued; no-op unless FLAG (exact fallback: full low-20 hist of
// the winning top-bucket into the dedicated H2SLOW region).
__global__ __launch_bounds__(1024) void fb_low(const u32* __restrict__ x,
                                               u32* __restrict__ ws,
                                               long long n, u32 k) {
  __shared__ u32 s[1024];
  __shared__ u32 resB1;
  if (ws[FLAG] == 0u) return;  // uniform

  const u32* g1 = ws + G1;
  u32* h2 = ws + H2S;
  const int t = threadIdx.x;
  {
    const uint2 c2 = ((const uint2*)g1)[t];
    const u32 sum = c2.x + c2.y;
    s[t] = sum;
    __syncthreads();
    for (int off = 1; off < 1024; off <<= 1) {
      u32 add = (t >= off) ? s[t - off] : 0u;
      __syncthreads();
      s[t] += add;
      __syncthreads();
    }
    u32 ex = s[t] - sum;
    if (k >= ex && k < ex + c2.x) resB1 = 2 * t;
    ex += c2.x;
    if (k >= ex && k < ex + c2.y) resB1 = 2 * t + 1;
    __syncthreads();
  }
  const u32 B1 = resB1;

  const long long n4 = n >> 2;
  const long long stride = (long long)gridDim.x * 1024;
  const uint4* x4 = (const uint4*)x;
  for (long long i = (long long)blockIdx.x * 1024 + t; i < n4; i += stride) {
    uint4 v = x4[i];
    u32 a;
    a = v.x & 0x7fffffffu; if ((a >> 20) == B1) atomicAdd(&h2[a & 0xFFFFFu], 1u);
    a = v.y & 0x7fffffffu; if ((a >> 20) == B1) atomicAdd(&h2[a & 0xFFFFFu], 1u);
    a = v.z & 0x7fffffffu; if ((a >> 20) == B1) atomicAdd(&h2[a & 0xFFFFFu], 1u);
    a = v.w & 0x7fffffffu; if ((a >> 20) == B1) atomicAdd(&h2[a & 0xFFFFFu], 1u);
  }
  for (long long i = (n4 << 2) + (long long)blockIdx.x * 1024 + t; i < n;
       i += stride) {
    const u32 a = x[i] & 0x7fffffffu;
    if ((a >> 20) == B1) atomicAdd(&h2[a & 0xFFFFFu], 1u);
  }
}

// fast: blocks 0..255 sum h2fine[b*1024 .. +1024) -> cs[b]
// slow: all 1024 blocks sum H2SLOW[b*1024 .. +1024) -> cs[b]
__global__ __launch_bounds__(256) void chunk_reduce(u32* __restrict__ ws,
                                                    u32 k) {
  const int t = threadIdx.x;
  const u32* base;
  if (ws[FLAG] != 0u) {
    base = ws + H2S;
  } else {
    if (blockIdx.x >= 256) return;
    base = ws + H2F;
  }
  u32* cs = ws + CS;
  uint4 v = ((const uint4*)(base + (size_t)blockIdx.x * 1024))[t];
  u32 sum = v.x + v.y + v.z + v.w;
#pragma unroll
  for (int off = 32; off > 0; off >>= 1) sum += __shfl_down(sum, off, 64);
  __shared__ u32 w[4];
  if ((t & 63) == 0) w[t >> 6] = sum;
  __syncthreads();
  if (t == 0) cs[blockIdx.x] = w[0] + w[1] + w[2] + w[3];
}

__global__ __launch_bounds__(1024) void quantize(const float* __restrict__ x,
                                                 float* __restrict__ out,
                                                 const u32* __restrict__ ws,
                                                 const float* __restrict__ gamma,
                                                 long long n, u32 k) {
  __shared__ u32 s[1024];
  __shared__ u32 r0, r1;
  __shared__ float fscale;
  const u32* cs = ws + CS;
  const int t = threadIdx.x;
  const int flag = (ws[FLAG] != 0u);

  // scan A: k1 (+ B1 on slow path)
  u32 B1 = 0, k1;
  const u32* h2base;
  if (!flag) {
    k1 = k - ws[BC];  // exact: validity checked by fb_top (k1 < c_in)
    h2base = ws + H2F;
  } else {
    const uint2 c2 = ((const uint2*)(ws + G1))[t];
    const u32 sum = c2.x + c2.y;
    s[t] = sum;
    __syncthreads();
    for (int off = 1; off < 1024; off <<= 1) {
      u32 add = (t >= off) ? s[t - off] : 0u;
      __syncthreads();
      s[t] += add;
      __syncthreads();
    }
    u32 ex = s[t] - sum;
    if (k >= ex && k < ex + c2.x) { r0 = 2u * t; r1 = k - ex; }
    ex += c2.x;
    if (k >= ex && k < ex + c2.y) { r0 = 2u * t + 1u; r1 = k - ex; }
    __syncthreads();
    B1 = r0; k1 = r1;
    h2base = ws + H2S;
  }
  // scan B: cs -> (chunk, k2). fast: 256 live entries (pad 0); slow: 1024.
  u32 chunk, k2;
  {
    const u32 c = (!flag && t >= 256) ? 0u : cs[t];
    __syncthreads();  // protect scan-A s[] reads before rewrite
    s[t] = c;
    __syncthreads();
    for (int off = 1; off < 1024; off <<= 1) {
      u32 add = (t >= off) ? s[t - off] : 0u;
      __syncthreads();
      s[t] += add;
      __syncthreads();
    }
    u32 ex = s[t] - c;
    if (c && k1 >= ex && k1 < ex + c) { r0 = (u32)t; r1 = k1 - ex; }
    __syncthreads();
    chunk = r0; k2 = r1;
  }
  // scan C: hist[chunk*1024 + t] -> exact bits -> scale
  {
    const u32 c = h2base[(size_t)chunk * 1024 + t];
    __syncthreads();
    s[t] = c;
    __syncthreads();
    for (int off = 1; off < 1024; off <<= 1) {
      u32 add = (t >= off) ? s[t - off] : 0u;
      __syncthreads();
      s[t] += add;
      __syncthreads();
    }
    u32 ex = s[t] - c;
    if (c && k2 >= ex && k2 < ex + c) {
      const u32 bits = flag ? ((B1 << 20) | (chunk * 1024u + (u32)t))
                            : (FINE_LO + chunk * 1024u + (u32)t);
      const float q = __uint_as_float(bits);
      float gm = gamma[0];
      gm = fminf(fmaxf(gm, 0.1f), 10.0f);
      fscale = (q / 127.0f) * gm;
    }
    __syncthreads();
  }
  const float scale = fscale;

  // hot loop: R4-proven 2 loads + 2 NT stores in flight
  const long long n4 = n >> 2;
  const float4* x4 = (const float4*)x;
  nfloat4* o4 = (nfloat4*)out;
#define QUANT(v, o)                                                        \
  do {                                                                     \
    (o).x = fminf(fmaxf(rintf((v).x / scale), -128.0f), 127.0f) * scale;   \
    (o).y = fminf(fmaxf(rintf((v).y / scale), -128.0f), 127.0f) * scale;   \
    (o).z = fminf(fmaxf(rintf((v).z / scale), -128.0f), 127.0f) * scale;   \
    (o).w = fminf(fmaxf(rintf((v).w / scale), -128.0f), 127.0f) * scale;   \
  } while (0)
  const long long CH = (long long)gridDim.x * 2048;
  long long i = (long long)blockIdx.x * 2048 + t;
  for (; i + 1024 < n4; i += CH) {
    float4 va = x4[i];
    float4 vb = x4[i + 1024];
    nfloat4 oa, ob;
    QUANT(va, oa);
    QUANT(vb, ob);
    __builtin_nontemporal_store(oa, &o4[i]);
    __builtin_nontemporal_store(ob, &o4[i + 1024]);
  }
  if (i < n4) {
    float4 v = x4[i];
    nfloat4 o;
    QUANT(v, o);
    __builtin_nontemporal_store(o, &o4[i]);
  }
#undef QUANT
  for (long long j = (n4 << 2) + (long long)blockIdx.x * 1024 + t; j < n;
       j += (long long)gridDim.x * 1024) {
    float v = x[j];
    out[j] = fminf(fmaxf(rintf(v / scale), -128.0f), 127.0f) * scale;
  }
}

extern "C" void kernel_launch(void* const* d_in, const int* in_sizes, int n_in,
                              void* d_out, int out_size, void* d_ws,
                              size_t ws_size, hipStream_t stream) {
  const u32* xbits = (const u32*)d_in[0];
  const float* gamma = (const float*)d_in[1];
  const long long n = (long long)in_sizes[0];
  u32* ws = (u32*)d_ws;

  const u32 k = (u32)llround(0.99 * (double)n);
  // fast path needs headers + H2SLOW + H2FINE = ~5.3 MB of ws
  const int cap_ok = (ws_size >= (size_t)ZERO_FAST * sizeof(u32)) ? 1 : 0;
  const size_t zero_u32 = cap_ok ? (size_t)ZERO_FAST : (size_t)ZERO_SLOW;

  (void)hipMemsetAsync(ws, 0, zero_u32 * sizeof(u32), stream);
  scan_top<<<512, 1024, 0, stream>>>(xbits, ws, n, cap_ok);
  fb_top<<<512, 1024, 0, stream>>>(xbits, ws, n, k, cap_ok ? 0 : 1);
  fb_low<<<512, 1024, 0, stream>>>(xbits, ws, n, k);
  chunk_reduce<<<1024, 256, 0, stream>>>(ws, k);
  quantize<<<512, 1024, 0, stream>>>((const float*)d_in[0], (float*)d_out, ws,
                                     gamma, n, k);
}